// Round 4
// baseline (1395.023 us; speedup 1.0000x reference)
//
#include <hip/hip_runtime.h>
#include <hip/hip_bf16.h>

typedef __bf16 bf16_t;
typedef __bf16 bf16x8 __attribute__((ext_vector_type(8)));
typedef __bf16 bf16x4 __attribute__((ext_vector_type(4)));
typedef __bf16 bf16x2 __attribute__((ext_vector_type(2)));
typedef float f32x4 __attribute__((ext_vector_type(4)));

#define MFMA16(a,b,c) __builtin_amdgcn_mfma_f32_16x16x32_bf16((a),(b),(c),0,0,0)
#define AS3(p) ((__attribute__((address_space(3))) void*)(p))
#define AS1(p) ((const __attribute__((address_space(1))) void*)(p))

constexpr int B_ = 4, L_ = 2048, E_ = 2048, H_ = 16, HD_ = 128;
constexpr size_t QK_ELEMS = (size_t)B_ * H_ * L_ * HD_;    // 16,777,216
constexpr size_t NX = (size_t)B_ * L_ * E_;                // 16,777,216
constexpr size_t NW = (size_t)3 * E_ * E_;                 // 12,582,912

// ---------------------------------------------------------------------------
// Kernel 0: fp32 -> bf16 conversion of X and W into one contiguous dst
// (dst lives in d_out's first 58.7MB; overwritten later by attn's output).
// ---------------------------------------------------------------------------
__global__ __launch_bounds__(256) void cvt(
    const float* __restrict__ X, const float* __restrict__ W, bf16_t* __restrict__ dst)
{
  size_t e = ((size_t)blockIdx.x * 256 + threadIdx.x) * 4;
  f32x4 v = (e < NX) ? *(const f32x4*)&X[e] : *(const f32x4*)&W[e - NX];
  bf16x4 o;
  for (int u = 0; u < 4; ++u) o[u] = (__bf16)v[u];
  *(bf16x4*)&dst[e] = o;
}

// ---------------------------------------------------------------------------
// Kernel 1: y = Xb @ Wb^T + b  (bf16 inputs, m97 structure)
// 128x128 tile, BK=32, 4 waves 2x2, global_load_lds width=16 staging.
// Epilogue scatters q,k -> [B,H,L,HD] and v -> vT [B,H,HD,L] (bf16).
// ---------------------------------------------------------------------------
__global__ __launch_bounds__(256) void gemm_qkv(
    const bf16_t* __restrict__ Xb, const bf16_t* __restrict__ Wb, const float* __restrict__ bias,
    bf16_t* __restrict__ q, bf16_t* __restrict__ k, bf16_t* __restrict__ vT)
{
  __shared__ alignas(16) bf16_t As[128 * 32];   // [m][k] packed, 64B rows
  __shared__ alignas(16) bf16_t Bs[128 * 32];   // [n][k] packed
  const int tid = threadIdx.x;
  const int wave = tid >> 6, lane = tid & 63;
  const int wm = wave >> 1, wn = wave & 1;
  const int m0 = blockIdx.y * 128, n0 = blockIdx.x * 128;
  const int rowf = lane & 15, kq8 = (lane >> 4) * 8;

  const int srow = wave * 32 + (lane >> 2);
  const int scol = (lane & 3) * 8;
  const bf16_t* gA0 = &Xb[(size_t)(m0 + srow) * E_ + scol];
  const bf16_t* gB0 = &Wb[(size_t)(n0 + srow) * E_ + scol];
  bf16_t* lA0 = &As[(wave * 32) * 32];
  bf16_t* lA1 = &As[(wave * 32 + 16) * 32];
  bf16_t* lB0 = &Bs[(wave * 32) * 32];
  bf16_t* lB1 = &Bs[(wave * 32 + 16) * 32];

  const f32x4 fzero = {0.f, 0.f, 0.f, 0.f};
  f32x4 acc[4][4];
  for (int i = 0; i < 4; ++i)
    for (int j = 0; j < 4; ++j) acc[i][j] = fzero;

  for (int k0 = 0; k0 < E_; k0 += 32) {
    __syncthreads();
    __builtin_amdgcn_global_load_lds(AS1(gA0 + k0),            AS3(lA0), 16, 0, 0);
    __builtin_amdgcn_global_load_lds(AS1(gA0 + 16 * E_ + k0),  AS3(lA1), 16, 0, 0);
    __builtin_amdgcn_global_load_lds(AS1(gB0 + k0),            AS3(lB0), 16, 0, 0);
    __builtin_amdgcn_global_load_lds(AS1(gB0 + 16 * E_ + k0),  AS3(lB1), 16, 0, 0);
    __syncthreads();
    bf16x8 af[4], bfr[4];
    for (int mt = 0; mt < 4; ++mt) af[mt]  = *(const bf16x8*)&As[(wm * 64 + mt * 16 + rowf) * 32 + kq8];
    for (int nt = 0; nt < 4; ++nt) bfr[nt] = *(const bf16x8*)&Bs[(wn * 64 + nt * 16 + rowf) * 32 + kq8];
    for (int mt = 0; mt < 4; ++mt)
      for (int nt = 0; nt < 4; ++nt)
        acc[mt][nt] = MFMA16(af[mt], bfr[nt], acc[mt][nt]);
  }

  const int b  = m0 >> 11;
  const int l0 = m0 & (L_ - 1);
  const int h  = n0 / 384;
  const int which = (n0 % 384) >> 7;  // 0=q 1=k 2=v

  float bcol[4];
  for (int nt = 0; nt < 4; ++nt)
    bcol[nt] = bias[n0 + wn * 64 + nt * 16 + (lane & 15)];

  if (which < 2) {
    bf16_t* base = ((which == 0) ? q : k) + ((size_t)(b * H_ + h) * L_) * HD_;
    for (int mt = 0; mt < 4; ++mt)
      for (int r = 0; r < 4; ++r) {
        int l = l0 + wm * 64 + mt * 16 + ((lane >> 4) << 2) + r;
        bf16_t* rowp = base + (size_t)l * HD_;
        for (int nt = 0; nt < 4; ++nt) {
          int hd = wn * 64 + nt * 16 + (lane & 15);
          rowp[hd] = (__bf16)(acc[mt][nt][r] + bcol[nt]);
        }
      }
  } else {
    bf16_t* base = vT + ((size_t)(b * H_ + h) * HD_) * L_;
    for (int mt = 0; mt < 4; ++mt)
      for (int r = 0; r < 4; ++r) {
        int l = l0 + wm * 64 + mt * 16 + ((lane >> 4) << 2) + r;
        for (int nt = 0; nt < 4; ++nt) {
          int hd = wn * 64 + nt * 16 + (lane & 15);
          base[(size_t)hd * L_ + l] = (__bf16)(acc[mt][nt][r] + bcol[nt]);
        }
      }
  }
}

// ---------------------------------------------------------------------------
// Kernel 2: in-place L2 normalize each 128-elem row of q and k (1 wave/row)
// ---------------------------------------------------------------------------
__global__ __launch_bounds__(256) void norm_qk(bf16_t* __restrict__ q, bf16_t* __restrict__ kk)
{
  const int gw = blockIdx.x * 4 + (threadIdx.x >> 6);
  const int lane = threadIdx.x & 63;
  const int rows_per = B_ * H_ * L_;
  bf16_t* base = (gw < rows_per) ? q : kk;
  int row = (gw < rows_per) ? gw : gw - rows_per;
  bf16_t* p = base + (size_t)row * HD_ + lane * 2;
  bf16x2 v2 = *(const bf16x2*)p;
  float a = (float)v2.x, bb = (float)v2.y;
  float ss = a * a + bb * bb;
  for (int off = 32; off; off >>= 1) ss += __shfl_xor(ss, off);
  float sc = 1.0f / fmaxf(sqrtf(ss), 1e-12f);
  v2.x = (__bf16)(a * sc);
  v2.y = (__bf16)(bb * sc);
  *(bf16x2*)p = v2;
}

// ---------------------------------------------------------------------------
// Kernel 3: flash attention v2. BQ=128, BKV=128, 4 waves (32 q-rows each).
// Q fragments in REGISTERS (loop-invariant). LDS: KPs 32KB (K during QK^T,
// aliased as P after) + Vts 32KB = 64KB -> 2 blk/CU. 3 barriers/iter, 16 iters.
// PV reads only same-wave P rows -> no barrier between P-write and PV.
// ---------------------------------------------------------------------------
__device__ __forceinline__ int swz128(int r, int c) {
  return r * 128 + ((((c >> 3) ^ (r & 15)) & 15) << 3) + (c & 7);
}

__global__ __launch_bounds__(256, 2) void attn(
    const bf16_t* __restrict__ q, const bf16_t* __restrict__ k,
    const bf16_t* __restrict__ vT, float* __restrict__ out)
{
  __shared__ alignas(16) bf16_t KPs[128 * 128];  // K [j][d] -> P [m][j]
  __shared__ alignas(16) bf16_t Vts[128 * 128];  // [d][j]

  const int tid = threadIdx.x, wave = tid >> 6, lane = tid & 63;
  const int bh = blockIdx.y;
  const int q0 = blockIdx.x * 128;
  const int rowf = lane & 15, kq8 = (lane >> 4) * 8;

  // Q fragments in registers: rows wave*32 + mt*16 + rowf, k-chunks kt*32+kq8
  const bf16_t* qbase = q + ((size_t)bh * L_ + q0) * HD_;
  bf16x8 aq[2][4];
  for (int mt = 0; mt < 2; ++mt)
    for (int kt = 0; kt < 4; ++kt)
      aq[mt][kt] = *(const bf16x8*)&qbase[(size_t)(wave * 32 + mt * 16 + rowf) * HD_ + kt * 32 + kq8];

  const f32x4 fzero = {0.f, 0.f, 0.f, 0.f};
  f32x4 o[2][8];
  for (int mt = 0; mt < 2; ++mt)
    for (int nt = 0; nt < 8; ++nt) o[mt][nt] = fzero;
  float mrow[2][4], lrow[2][4];
  for (int mt = 0; mt < 2; ++mt)
    for (int r = 0; r < 4; ++r) { mrow[mt][r] = -1e30f; lrow[mt][r] = 0.f; }

  const bf16_t* kbh = k + (size_t)bh * L_ * HD_;
  const bf16_t* vbh = vT + (size_t)bh * HD_ * L_;

  for (int j0 = 0; j0 < L_; j0 += 128) {
    __syncthreads();  // guard restage vs previous iteration's K/P/V reads
    for (int i = 0; i < 8; ++i) {
      int e = (i * 256 + tid) * 8;
      int r = e >> 7, c = e & 127;
      *(f32x4*)&KPs[swz128(r, c)] = *(const f32x4*)&kbh[(size_t)(j0 + r) * HD_ + c];
    }
    for (int i = 0; i < 8; ++i) {
      int e = (i * 256 + tid) * 8;
      int d = e >> 7, c = e & 127;
      *(f32x4*)&Vts[swz128(d, c)] = *(const f32x4*)&vbh[(size_t)d * L_ + j0 + c];
    }
    __syncthreads();

    // S = Q K^T  (A = Q regs, B = K rows)
    f32x4 s[2][8];
    for (int mt = 0; mt < 2; ++mt)
      for (int nt = 0; nt < 8; ++nt) s[mt][nt] = fzero;
    for (int kt = 0; kt < 4; ++kt) {
      for (int nt = 0; nt < 8; ++nt) {
        bf16x8 bk = *(const bf16x8*)&KPs[swz128(nt * 16 + rowf, kt * 32 + kq8)];
        for (int mt = 0; mt < 2; ++mt)
          s[mt][nt] = MFMA16(aq[mt][kt], bk, s[mt][nt]);
      }
    }
    __syncthreads();  // all waves done reading K before it becomes P

    // online softmax (rows (lane>>4)*4+r shared by S and O C-layouts)
    for (int mt = 0; mt < 2; ++mt) {
      for (int r = 0; r < 4; ++r) {
        float mx = s[mt][0][r];
        for (int nt = 1; nt < 8; ++nt) mx = fmaxf(mx, s[mt][nt][r]);
        for (int off = 8; off; off >>= 1) mx = fmaxf(mx, __shfl_xor(mx, off));
        float mnew = fmaxf(mrow[mt][r], mx);
        float alpha = __expf(mrow[mt][r] - mnew);
        mrow[mt][r] = mnew;
        float ps = 0.f;
        for (int nt = 0; nt < 8; ++nt) {
          float p0 = __expf(s[mt][nt][r] - mnew);
          s[mt][nt][r] = p0;
          ps += p0;
        }
        for (int off = 8; off; off >>= 1) ps += __shfl_xor(ps, off);
        lrow[mt][r] = lrow[mt][r] * alpha + ps;
        for (int nt = 0; nt < 8; ++nt) o[mt][nt][r] *= alpha;
      }
    }
    // P: C-layout regs -> [m][j] in KPs (own-wave rows only)
    for (int mt = 0; mt < 2; ++mt)
      for (int nt = 0; nt < 8; ++nt)
        for (int r = 0; r < 4; ++r) {
          int rr = wave * 32 + mt * 16 + ((lane >> 4) << 2) + r;
          int cc = nt * 16 + (lane & 15);
          KPs[swz128(rr, cc)] = (__bf16)s[mt][nt][r];
        }
    // no barrier: PV A-frags below read only this wave's own rows

    // O += P @ V  (A = P rows, B = Vt rows; k = j)
    for (int kt = 0; kt < 4; ++kt) {
      bf16x8 ap[2];
      for (int mt = 0; mt < 2; ++mt)
        ap[mt] = *(const bf16x8*)&KPs[swz128(wave * 32 + mt * 16 + rowf, kt * 32 + kq8)];
      for (int nt = 0; nt < 8; ++nt) {
        bf16x8 bv = *(const bf16x8*)&Vts[swz128(nt * 16 + rowf, kt * 32 + kq8)];
        for (int mt = 0; mt < 2; ++mt)
          o[mt][nt] = MFMA16(ap[mt], bv, o[mt][nt]);
      }
    }
  }

  // epilogue: divide by softmax denom, write fp32 out [B][L][H][HD]
  const int b = bh >> 4, h = bh & 15;
  for (int mt = 0; mt < 2; ++mt) {
    for (int r = 0; r < 4; ++r) {
      float inv = 1.0f / lrow[mt][r];
      int l = q0 + wave * 32 + mt * 16 + ((lane >> 4) << 2) + r;
      float* op = out + (((size_t)b * L_ + l) * H_ + h) * HD_;
      for (int nt = 0; nt < 8; ++nt) {
        int d = nt * 16 + (lane & 15);
        op[d] = o[mt][nt][r] * inv;
      }
    }
  }
}

// ---------------------------------------------------------------------------
extern "C" void kernel_launch(void* const* d_in, const int* in_sizes, int n_in,
                              void* d_out, int out_size, void* d_ws, size_t ws_size,
                              hipStream_t stream)
{
  const float* X    = (const float*)d_in[0];   // [4,2048,2048] fp32
  const float* W    = (const float*)d_in[1];   // [6144,2048] fp32
  const float* bias = (const float*)d_in[2];   // [6144] fp32
  float* out = (float*)d_out;                  // [4,2048,2048] fp32

  // bf16 copies of X and W live inside d_out (58.7MB < 67.1MB); d_out is not
  // written until attn, which runs after gemm_qkv has consumed them.
  bf16_t* Xb = (bf16_t*)d_out;
  bf16_t* Wb = Xb + NX;

  bf16_t* q  = (bf16_t*)d_ws;                  // [B,H,L,HD] 32MB
  bf16_t* k  = q + QK_ELEMS;                   // 32MB
  bf16_t* vT = k + QK_ELEMS;                   // [B,H,HD,L] 32MB

  cvt<<<dim3((NX + NW) / (256 * 4)), 256, 0, stream>>>(X, W, Xb);
  gemm_qkv<<<dim3(48, 64), 256, 0, stream>>>(Xb, Wb, bias, q, k, vT);
  norm_qk<<<dim3(65536), 256, 0, stream>>>(q, k);
  attn<<<dim3(16, 64), 256, 0, stream>>>(q, k, vT, out);
}

// Round 5
// 1150.343 us; speedup vs baseline: 1.2127x; 1.2127x over previous
//
#include <hip/hip_runtime.h>
#include <hip/hip_bf16.h>

typedef __bf16 bf16_t;
typedef __bf16 bf16x8 __attribute__((ext_vector_type(8)));
typedef __bf16 bf16x4 __attribute__((ext_vector_type(4)));
typedef __bf16 bf16x2 __attribute__((ext_vector_type(2)));
typedef float f32x4 __attribute__((ext_vector_type(4)));

#define MFMA16(a,b,c) __builtin_amdgcn_mfma_f32_16x16x32_bf16((a),(b),(c),0,0,0)
#define AS3(p) ((__attribute__((address_space(3))) void*)(p))
#define AS1(p) ((const __attribute__((address_space(1))) void*)(p))

constexpr int B_ = 4, L_ = 2048, E_ = 2048, H_ = 16, HD_ = 128;
constexpr size_t QK_ELEMS = (size_t)B_ * H_ * L_ * HD_;    // 16,777,216
constexpr size_t NX = (size_t)B_ * L_ * E_;                // 16,777,216
constexpr size_t NW = (size_t)3 * E_ * E_;                 // 12,582,912

// ---------------------------------------------------------------------------
// Kernel 0: fp32 -> bf16 conversion of X and W into one contiguous dst
// (dst lives in d_out's first 58.7MB; overwritten later by attn's output).
// ---------------------------------------------------------------------------
__global__ __launch_bounds__(256) void cvt(
    const float* __restrict__ X, const float* __restrict__ W, bf16_t* __restrict__ dst)
{
  size_t e = ((size_t)blockIdx.x * 256 + threadIdx.x) * 4;
  f32x4 v = (e < NX) ? *(const f32x4*)&X[e] : *(const f32x4*)&W[e - NX];
  bf16x4 o;
  for (int u = 0; u < 4; ++u) o[u] = (__bf16)v[u];
  *(bf16x4*)&dst[e] = o;
}

// ---------------------------------------------------------------------------
// Kernel 1: y = Xb @ Wb^T + b  (bf16 inputs, m97 structure)
// 128x128 tile, BK=32, 4 waves 2x2, global_load_lds width=16 staging.
// Epilogue scatters q,k -> [B,H,L,HD] and v -> vT [B,H,HD,L] (bf16).
// ---------------------------------------------------------------------------
__global__ __launch_bounds__(256) void gemm_qkv(
    const bf16_t* __restrict__ Xb, const bf16_t* __restrict__ Wb, const float* __restrict__ bias,
    bf16_t* __restrict__ q, bf16_t* __restrict__ k, bf16_t* __restrict__ vT)
{
  __shared__ alignas(16) bf16_t As[128 * 32];   // [m][k] packed, 64B rows
  __shared__ alignas(16) bf16_t Bs[128 * 32];   // [n][k] packed
  const int tid = threadIdx.x;
  const int wave = tid >> 6, lane = tid & 63;
  const int wm = wave >> 1, wn = wave & 1;
  const int m0 = blockIdx.y * 128, n0 = blockIdx.x * 128;
  const int rowf = lane & 15, kq8 = (lane >> 4) * 8;

  const int srow = wave * 32 + (lane >> 2);
  const int scol = (lane & 3) * 8;
  const bf16_t* gA0 = &Xb[(size_t)(m0 + srow) * E_ + scol];
  const bf16_t* gB0 = &Wb[(size_t)(n0 + srow) * E_ + scol];
  bf16_t* lA0 = &As[(wave * 32) * 32];
  bf16_t* lA1 = &As[(wave * 32 + 16) * 32];
  bf16_t* lB0 = &Bs[(wave * 32) * 32];
  bf16_t* lB1 = &Bs[(wave * 32 + 16) * 32];

  const f32x4 fzero = {0.f, 0.f, 0.f, 0.f};
  f32x4 acc[4][4];
  for (int i = 0; i < 4; ++i)
    for (int j = 0; j < 4; ++j) acc[i][j] = fzero;

  for (int k0 = 0; k0 < E_; k0 += 32) {
    __syncthreads();
    __builtin_amdgcn_global_load_lds(AS1(gA0 + k0),            AS3(lA0), 16, 0, 0);
    __builtin_amdgcn_global_load_lds(AS1(gA0 + 16 * E_ + k0),  AS3(lA1), 16, 0, 0);
    __builtin_amdgcn_global_load_lds(AS1(gB0 + k0),            AS3(lB0), 16, 0, 0);
    __builtin_amdgcn_global_load_lds(AS1(gB0 + 16 * E_ + k0),  AS3(lB1), 16, 0, 0);
    __syncthreads();
    bf16x8 af[4], bfr[4];
    for (int mt = 0; mt < 4; ++mt) af[mt]  = *(const bf16x8*)&As[(wm * 64 + mt * 16 + rowf) * 32 + kq8];
    for (int nt = 0; nt < 4; ++nt) bfr[nt] = *(const bf16x8*)&Bs[(wn * 64 + nt * 16 + rowf) * 32 + kq8];
    for (int mt = 0; mt < 4; ++mt)
      for (int nt = 0; nt < 4; ++nt)
        acc[mt][nt] = MFMA16(af[mt], bfr[nt], acc[mt][nt]);
  }

  const int b  = m0 >> 11;
  const int l0 = m0 & (L_ - 1);
  const int h  = n0 / 384;
  const int which = (n0 % 384) >> 7;  // 0=q 1=k 2=v

  float bcol[4];
  for (int nt = 0; nt < 4; ++nt)
    bcol[nt] = bias[n0 + wn * 64 + nt * 16 + (lane & 15)];

  if (which < 2) {
    bf16_t* base = ((which == 0) ? q : k) + ((size_t)(b * H_ + h) * L_) * HD_;
    for (int mt = 0; mt < 4; ++mt)
      for (int r = 0; r < 4; ++r) {
        int l = l0 + wm * 64 + mt * 16 + ((lane >> 4) << 2) + r;
        bf16_t* rowp = base + (size_t)l * HD_;
        for (int nt = 0; nt < 4; ++nt) {
          int hd = wn * 64 + nt * 16 + (lane & 15);
          rowp[hd] = (__bf16)(acc[mt][nt][r] + bcol[nt]);
        }
      }
  } else {
    bf16_t* base = vT + ((size_t)(b * H_ + h) * HD_) * L_;
    for (int mt = 0; mt < 4; ++mt)
      for (int r = 0; r < 4; ++r) {
        int l = l0 + wm * 64 + mt * 16 + ((lane >> 4) << 2) + r;
        for (int nt = 0; nt < 4; ++nt) {
          int hd = wn * 64 + nt * 16 + (lane & 15);
          base[(size_t)hd * L_ + l] = (__bf16)(acc[mt][nt][r] + bcol[nt]);
        }
      }
  }
}

// ---------------------------------------------------------------------------
// Kernel 2: in-place L2 normalize each 128-elem row of q and k (1 wave/row)
// ---------------------------------------------------------------------------
__global__ __launch_bounds__(256) void norm_qk(bf16_t* __restrict__ q, bf16_t* __restrict__ kk)
{
  const int gw = blockIdx.x * 4 + (threadIdx.x >> 6);
  const int lane = threadIdx.x & 63;
  const int rows_per = B_ * H_ * L_;
  bf16_t* base = (gw < rows_per) ? q : kk;
  int row = (gw < rows_per) ? gw : gw - rows_per;
  bf16_t* p = base + (size_t)row * HD_ + lane * 2;
  bf16x2 v2 = *(const bf16x2*)p;
  float a = (float)v2.x, bb = (float)v2.y;
  float ss = a * a + bb * bb;
  for (int off = 32; off; off >>= 1) ss += __shfl_xor(ss, off);
  float sc = 1.0f / fmaxf(sqrtf(ss), 1e-12f);
  v2.x = (__bf16)(a * sc);
  v2.y = (__bf16)(bb * sc);
  *(bf16x2*)p = v2;
}

// ---------------------------------------------------------------------------
// Kernel 3: flash attention v3. BQ=128, BKV=128 (two 64-col sub-steps),
// 4 waves x 32 q-rows. Q in registers. LDS: Ks 32K + Vts 32K + Ps 16K = 80KB
// -> 2 blk/CU. Ps rows are wave-private -> P-write/PV need NO barrier;
// K/V are read-only during compute -> only 2 barriers per 128-col tile.
// s[2][4] (32 regs) keeps peak pressure ~round-3 level; NO launch_bounds
// min-waves hint (it clamped VGPRs to 128 and caused spills in round 4).
// ---------------------------------------------------------------------------
__device__ __forceinline__ int swz128(int r, int c) {
  return r * 128 + ((((c >> 3) ^ (r & 15)) & 15) << 3) + (c & 7);
}
__device__ __forceinline__ int swz64(int r, int c) {
  return r * 64 + ((((c >> 3) ^ (r & 7)) & 7) << 3) + (c & 7);
}

__global__ __launch_bounds__(256) void attn(
    const bf16_t* __restrict__ q, const bf16_t* __restrict__ k,
    const bf16_t* __restrict__ vT, float* __restrict__ out)
{
  __shared__ alignas(16) bf16_t Ks[128 * 128];   // [j][d]
  __shared__ alignas(16) bf16_t Vts[128 * 128];  // [d][j]
  __shared__ alignas(16) bf16_t Ps[128 * 64];    // [m][j-sub], wave-private rows

  const int tid = threadIdx.x, wave = tid >> 6, lane = tid & 63;
  const int bh = blockIdx.y;
  const int q0 = blockIdx.x * 128;
  const int rowf = lane & 15, kq8 = (lane >> 4) * 8;
  const int crow = (lane >> 4) << 2;  // C/D row base

  // Q fragments in registers (loop-invariant): 8x bf16x8 = 32 VGPRs
  const bf16_t* qbase = q + ((size_t)bh * L_ + q0) * HD_;
  bf16x8 aq[2][4];
  for (int mt = 0; mt < 2; ++mt)
    for (int kt = 0; kt < 4; ++kt)
      aq[mt][kt] = *(const bf16x8*)&qbase[(size_t)(wave * 32 + mt * 16 + rowf) * HD_ + kt * 32 + kq8];

  const f32x4 fzero = {0.f, 0.f, 0.f, 0.f};
  f32x4 o[2][8];
  for (int mt = 0; mt < 2; ++mt)
    for (int nt = 0; nt < 8; ++nt) o[mt][nt] = fzero;
  float mrow[2][4], lrow[2][4];
  for (int mt = 0; mt < 2; ++mt)
    for (int r = 0; r < 4; ++r) { mrow[mt][r] = -1e30f; lrow[mt][r] = 0.f; }

  const bf16_t* kbh = k + (size_t)bh * L_ * HD_;
  const bf16_t* vbh = vT + (size_t)bh * HD_ * L_;

  for (int j0 = 0; j0 < L_; j0 += 128) {
    __syncthreads();  // prior iteration's K/V reads must finish before restage
    for (int i = 0; i < 8; ++i) {
      int e = (i * 256 + tid) * 8;
      int r = e >> 7, c = e & 127;
      *(f32x4*)&Ks[swz128(r, c)] = *(const f32x4*)&kbh[(size_t)(j0 + r) * HD_ + c];
    }
    for (int i = 0; i < 8; ++i) {
      int e = (i * 256 + tid) * 8;
      int d = e >> 7, c = e & 127;
      *(f32x4*)&Vts[swz128(d, c)] = *(const f32x4*)&vbh[(size_t)d * L_ + j0 + c];
    }
    __syncthreads();

    for (int sub = 0; sub < 2; ++sub) {
      // S(64 cols) = Q K^T
      f32x4 s[2][4];
      for (int mt = 0; mt < 2; ++mt)
        for (int nt = 0; nt < 4; ++nt) s[mt][nt] = fzero;
      for (int kt = 0; kt < 4; ++kt)
        for (int nt = 0; nt < 4; ++nt) {
          bf16x8 bk = *(const bf16x8*)&Ks[swz128((sub * 4 + nt) * 16 + rowf, kt * 32 + kq8)];
          for (int mt = 0; mt < 2; ++mt)
            s[mt][nt] = MFMA16(aq[mt][kt], bk, s[mt][nt]);
        }

      // online softmax (rows crow+r shared by S and O C-layouts)
      for (int mt = 0; mt < 2; ++mt)
        for (int r = 0; r < 4; ++r) {
          float mx = fmaxf(fmaxf(s[mt][0][r], s[mt][1][r]), fmaxf(s[mt][2][r], s[mt][3][r]));
          for (int off = 8; off; off >>= 1) mx = fmaxf(mx, __shfl_xor(mx, off));
          float mnew = fmaxf(mrow[mt][r], mx);
          float alpha = __expf(mrow[mt][r] - mnew);
          mrow[mt][r] = mnew;
          float ps = 0.f;
          for (int nt = 0; nt < 4; ++nt) {
            float p0 = __expf(s[mt][nt][r] - mnew);
            s[mt][nt][r] = p0;
            ps += p0;
          }
          for (int off = 8; off; off >>= 1) ps += __shfl_xor(ps, off);
          lrow[mt][r] = lrow[mt][r] * alpha + ps;
          for (int nt = 0; nt < 8; ++nt) o[mt][nt][r] *= alpha;
        }

      // P -> Ps (own-wave rows only; no cross-wave hazard, no barrier)
      for (int mt = 0; mt < 2; ++mt)
        for (int nt = 0; nt < 4; ++nt)
          for (int r = 0; r < 4; ++r)
            Ps[swz64(wave * 32 + mt * 16 + crow + r, nt * 16 + rowf)] = (__bf16)s[mt][nt][r];

      // O += P @ V  (A = own Ps rows; B = Vts rows, cols sub*64..)
      for (int kt = 0; kt < 2; ++kt) {
        bf16x8 ap[2];
        for (int mt = 0; mt < 2; ++mt)
          ap[mt] = *(const bf16x8*)&Ps[swz64(wave * 32 + mt * 16 + rowf, kt * 32 + kq8)];
        for (int nt = 0; nt < 8; ++nt) {
          bf16x8 bv = *(const bf16x8*)&Vts[swz128(nt * 16 + rowf, sub * 64 + kt * 32 + kq8)];
          for (int mt = 0; mt < 2; ++mt)
            o[mt][nt] = MFMA16(ap[mt], bv, o[mt][nt]);
        }
      }
    }
  }

  // epilogue: divide by softmax denom, write fp32 out [B][L][H][HD]
  const int b = bh >> 4, h = bh & 15;
  for (int mt = 0; mt < 2; ++mt) {
    for (int r = 0; r < 4; ++r) {
      float inv = 1.0f / lrow[mt][r];
      int l = q0 + wave * 32 + mt * 16 + crow + r;
      float* op = out + (((size_t)b * L_ + l) * H_ + h) * HD_;
      for (int nt = 0; nt < 8; ++nt) {
        int d = nt * 16 + rowf;
        op[d] = o[mt][nt][r] * inv;
      }
    }
  }
}

// ---------------------------------------------------------------------------
extern "C" void kernel_launch(void* const* d_in, const int* in_sizes, int n_in,
                              void* d_out, int out_size, void* d_ws, size_t ws_size,
                              hipStream_t stream)
{
  const float* X    = (const float*)d_in[0];   // [4,2048,2048] fp32
  const float* W    = (const float*)d_in[1];   // [6144,2048] fp32
  const float* bias = (const float*)d_in[2];   // [6144] fp32
  float* out = (float*)d_out;                  // [4,2048,2048] fp32

  // bf16 copies of X and W live inside d_out (58.7MB < 67.1MB); d_out is not
  // written until attn, which runs after gemm_qkv has consumed them.
  bf16_t* Xb = (bf16_t*)d_out;
  bf16_t* Wb = Xb + NX;

  bf16_t* q  = (bf16_t*)d_ws;                  // [B,H,L,HD] 32MB
  bf16_t* k  = q + QK_ELEMS;                   // 32MB
  bf16_t* vT = k + QK_ELEMS;                   // [B,H,HD,L] 32MB

  cvt<<<dim3((NX + NW) / (256 * 4)), 256, 0, stream>>>(X, W, Xb);
  gemm_qkv<<<dim3(48, 64), 256, 0, stream>>>(Xb, Wb, bias, q, k, vT);
  norm_qk<<<dim3(65536), 256, 0, stream>>>(q, k);
  attn<<<dim3(16, 64), 256, 0, stream>>>(q, k, vT, out);
}